// Round 3
// baseline (171.221 us; speedup 1.0000x reference)
//
#include <hip/hip_runtime.h>
#include <hip/hip_bf16.h>

#define BATCH 8192
#define DIN   4096
#define H1    128
#define NLAT  512
#define LAT   32

typedef short bf16x8 __attribute__((ext_vector_type(8)));
typedef float f32x4  __attribute__((ext_vector_type(4)));

static __device__ __forceinline__ unsigned short f2bf(float f) {
  union { float f; unsigned u; } v; v.f = f;
  return (unsigned short)((v.u + 0x7FFFu + ((v.u >> 16) & 1u)) >> 16);  // RNE
}

// ---- prep: W1 [4096][128] f32 -> W1T [128][4096] bf16 ----
__global__ void prep_w1t(const float* __restrict__ W1, unsigned short* __restrict__ W1T) {
  __shared__ float t[32][33];
  int k0 = blockIdx.x * 32;
  int n0 = blockIdx.y * 32;
  int tx = threadIdx.x & 31, ty = threadIdx.x >> 5;
#pragma unroll
  for (int i = 0; i < 32; i += 8)
    t[ty + i][tx] = W1[(size_t)(k0 + ty + i) * H1 + (n0 + tx)];
  __syncthreads();
#pragma unroll
  for (int i = 0; i < 32; i += 8)
    W1T[(size_t)(n0 + ty + i) * DIN + (k0 + tx)] = f2bf(t[tx][ty + i]);
}

// ---- prep: decoders flat [4096][32] f32 -> decT [32][4096] f32 ----
__global__ void prep_dect(const float* __restrict__ dec, float* __restrict__ decT) {
  __shared__ float t[32][33];
  int d0 = blockIdx.x * 32;
  int tx = threadIdx.x & 31, ty = threadIdx.x >> 5;
#pragma unroll
  for (int i = 0; i < 32; i += 8)
    t[ty + i][tx] = dec[(size_t)(d0 + ty + i) * LAT + tx];
  __syncthreads();
#pragma unroll
  for (int i = 0; i < 32; i += 8)
    decT[(size_t)(ty + i) * DIN + (d0 + tx)] = t[tx][ty + i];
}

// ---- gemm1: partial[si][8192][128] = x[:, ksl] @ W1[ksl, :] (bf16 MFMA) ----
// Software-pipelined: compile-time KLEN, full unroll, A prefetched one k-step
// ahead (keeps a 1KB/wave load in flight across the convert+MFMA phase), B
// issued at iter top so the unrolled scheduler hoists them early. ~92 VGPR.
template<int KLEN>
__global__ __launch_bounds__(256, 4) void gemm1_kernel(
    const float* __restrict__ x, const unsigned short* __restrict__ W1T,
    float* __restrict__ partial) {
  int w = (blockIdx.x << 2) + (threadIdx.x >> 6);
  int lane = threadIdx.x & 63;
  int rg = w & 511, si = w >> 9;
  int k0 = si * KLEN;
  int rbase = rg << 4;
  int kg = (lane >> 4) << 3;
  const float* xp = x + (size_t)(rbase + (lane & 15)) * DIN + k0 + kg;
  const unsigned short* bp = W1T + (size_t)(lane & 15) * DIN + k0 + kg;
  f32x4 acc[8];
#pragma unroll
  for (int i = 0; i < 8; i++) acc[i] = (f32x4){0.f, 0.f, 0.f, 0.f};

  f32x4 a0 = *(const f32x4*)xp;
  f32x4 a1 = *(const f32x4*)(xp + 4);
#pragma unroll
  for (int kk = 0; kk < KLEN; kk += 32) {
    // B fragments for this step — issued early, independent of A chain
    bf16x8 bv[8];
#pragma unroll
    for (int nn = 0; nn < 8; nn++)
      bv[nn] = *(const bf16x8*)(bp + (size_t)nn * 16 * DIN + kk);
    // prefetch next A while this step computes
    f32x4 na0, na1;
    if (kk + 32 < KLEN) {
      na0 = *(const f32x4*)(xp + kk + 32);
      na1 = *(const f32x4*)(xp + kk + 36);
    }
    union { bf16x8 v; unsigned short u[8]; } af;
#pragma unroll
    for (int j = 0; j < 4; j++) { af.u[j] = f2bf(a0[j]); af.u[4 + j] = f2bf(a1[j]); }
#pragma unroll
    for (int nn = 0; nn < 8; nn++)
      acc[nn] = __builtin_amdgcn_mfma_f32_16x16x32_bf16(af.v, bv[nn], acc[nn], 0, 0, 0);
    if (kk + 32 < KLEN) { a0 = na0; a1 = na1; }
  }
  // C/D layout (verified): col = lane&15, row = (lane>>4)*4 + j
  float* pb = partial + ((size_t)si * BATCH + rbase) * H1;
  int crow = (lane >> 4) << 2, ccol = lane & 15;
#pragma unroll
  for (int nn = 0; nn < 8; nn++)
#pragma unroll
    for (int j = 0; j < 4; j++)
      pb[(size_t)(crow + j) * H1 + nn * 16 + ccol] = acc[nn][j];
}

// ---- z_kernel: h = relu(sum partials + b1); z = h@W2+b2 -> zout;
//      zsum fold -> zsumg [BATCH][32]. 16 rows / block. ----
__global__ __launch_bounds__(256) void z_kernel(
    const float* __restrict__ partial, int kslices,
    const float* __restrict__ b1, const float* __restrict__ W2,
    const float* __restrict__ b2,
    float* __restrict__ zout, float* __restrict__ zsumg) {
  __shared__ float hs[16][128];
  __shared__ float zsp[16][32][4];
  int t = threadIdx.x;
  int rbase = blockIdx.x << 4;

  // phase 1: consolidate partials -> h in LDS
#pragma unroll
  for (int i = 0; i < 8; i++) {
    int idx = t + (i << 8);
    int r = idx >> 7, c = idx & 127;
    float s = b1[c];
    for (int si = 0; si < kslices; si++)
      s += partial[((size_t)si * BATCH + rbase + r) * H1 + c];
    hs[r][c] = fmaxf(s, 0.f);
  }
  __syncthreads();

  // phase 2: z. wave wq covers cols [wq*128, +128); lane -> c0, c0+64
  int wq = t >> 6, lane = t & 63;
  int c0 = (wq << 7) + lane;
  float acc0[16], acc1[16];
#pragma unroll
  for (int r = 0; r < 16; r++) { acc0[r] = 0.f; acc1[r] = 0.f; }
  for (int k4 = 0; k4 < 32; k4++) {
    float w2a[4], w2b[4];
#pragma unroll
    for (int j = 0; j < 4; j++) {
      w2a[j] = W2[(size_t)(k4 * 4 + j) * NLAT + c0];
      w2b[j] = W2[(size_t)(k4 * 4 + j) * NLAT + c0 + 64];
    }
#pragma unroll
    for (int rg = 0; rg < 4; rg++) {
      f32x4 hv[4];
#pragma unroll
      for (int rr = 0; rr < 4; rr++)
        hv[rr] = *(const f32x4*)&hs[rg * 4 + rr][k4 * 4];
#pragma unroll
      for (int rr = 0; rr < 4; rr++)
#pragma unroll
        for (int j = 0; j < 4; j++) {
          acc0[rg * 4 + rr] += hv[rr][j] * w2a[j];
          acc1[rg * 4 + rr] += hv[rr][j] * w2b[j];
        }
    }
  }
  float bb0 = b2[c0], bb1 = b2[c0 + 64];
#pragma unroll
  for (int r = 0; r < 16; r++) {
    float v0 = acc0[r] + bb0, v1 = acc1[r] + bb1;
    zout[(size_t)(rbase + r) * NLAT + c0] = v0;
    zout[(size_t)(rbase + r) * NLAT + c0 + 64] = v1;
    float ps = v0 + v1;               // two factors, same latent index
    ps += __shfl_xor(ps, 32);         // + complementary factor pair
    if (lane < 32) zsp[r][lane][wq] = ps;
  }
  __syncthreads();
  // consolidate 4 wave-partials -> zsum global (deterministic order)
#pragma unroll
  for (int i = 0; i < 2; i++) {
    int idx = t + (i << 8);
    int r = idx >> 5, l = idx & 31;
    f32x4 p4 = *(const f32x4*)&zsp[r][l][0];
    zsumg[(size_t)(rbase + r) * LAT + l] = p4[0] + p4[1] + p4[2] + p4[3];
  }
}

// ---- recon_kernel: rout[b][d] = sum_l zsum[b][l] * decT[l][d]. ----
__global__ __launch_bounds__(256) void recon_kernel(
    const float* __restrict__ zsumg, const float* __restrict__ decT,
    float* __restrict__ rout) {
  __shared__ float zs[32][32];
  int t = threadIdx.x;
  int rbase = (blockIdx.x >> 4) << 5;
  int dcol0 = (blockIdx.x & 15) << 8;
  {
    int r = t >> 3, c4 = (t & 7) << 2;
    *(f32x4*)&zs[r][c4] = *(const f32x4*)(zsumg + (size_t)(rbase + r) * LAT + c4);
  }
  __syncthreads();
  int wq = t >> 6, lane = t & 63;
  int r0 = wq << 3;
  int dcol = dcol0 + (lane << 2);
  f32x4 acc[8];
#pragma unroll
  for (int r = 0; r < 8; r++) acc[r] = (f32x4){0.f, 0.f, 0.f, 0.f};
#pragma unroll 8
  for (int l = 0; l < 32; l++) {
    f32x4 dv = *(const f32x4*)(decT + (size_t)l * DIN + dcol);
#pragma unroll
    for (int r = 0; r < 8; r++) {
      float zv = zs[r0 + r][l];
#pragma unroll
      for (int j = 0; j < 4; j++) acc[r][j] += zv * dv[j];
    }
  }
#pragma unroll
  for (int r = 0; r < 8; r++)
    *(f32x4*)(rout + (size_t)(rbase + r0 + r) * DIN + dcol) = acc[r];
}

extern "C" void kernel_launch(void* const* d_in, const int* in_sizes, int n_in,
                              void* d_out, int out_size, void* d_ws, size_t ws_size,
                              hipStream_t stream) {
  const float* x   = (const float*)d_in[0];
  const float* W1  = (const float*)d_in[1];
  const float* b1  = (const float*)d_in[2];
  const float* W2  = (const float*)d_in[3];
  const float* b2  = (const float*)d_in[4];
  const float* dec = (const float*)d_in[5];
  float* zout = (float*)d_out;
  float* rout = zout + (size_t)BATCH * NLAT;

  char* ws = (char*)d_ws;
  unsigned short* W1T = (unsigned short*)ws;                     // 1 MB
  float* decT  = (float*)(ws + (1u << 20));                      // 512 KB
  float* zsumg = (float*)(ws + (1u << 20) + (512u << 10));       // 1 MB
  float* partial = (float*)(ws + (2u << 20) + (512u << 10));     // ks * 4 MB
  const size_t fixed = (2u << 20) + (512u << 10);
  const size_t slice_bytes = (size_t)BATCH * H1 * 4;
  int ks = 1;
  if (ws_size >= fixed + 8 * slice_bytes)      ks = 8;
  else if (ws_size >= fixed + 4 * slice_bytes) ks = 4;
  else if (ws_size >= fixed + 2 * slice_bytes) ks = 2;

  prep_w1t<<<dim3(128, 4), 256, 0, stream>>>(W1, W1T);
  prep_dect<<<dim3(128), 256, 0, stream>>>(dec, decT);
  if (ks == 8)      gemm1_kernel<512><<<dim3(1024), 256, 0, stream>>>(x, W1T, partial);
  else if (ks == 4) gemm1_kernel<1024><<<dim3(512), 256, 0, stream>>>(x, W1T, partial);
  else if (ks == 2) gemm1_kernel<2048><<<dim3(256), 256, 0, stream>>>(x, W1T, partial);
  else              gemm1_kernel<4096><<<dim3(128), 256, 0, stream>>>(x, W1T, partial);
  z_kernel<<<dim3(512), 256, 0, stream>>>(partial, ks, b1, W2, b2, zout, zsumg);
  recon_kernel<<<dim3(4096), 256, 0, stream>>>(zsumg, decT, rout);
}

// Round 4
// 117.229 us; speedup vs baseline: 1.4606x; 1.4606x over previous
//
#include <hip/hip_runtime.h>
#include <hip/hip_bf16.h>

#define BATCH 8192
#define DIN   4096
#define H1    128
#define NLAT  512
#define LAT   32
#define KS    8
#define KLEN  (DIN / KS)   // 512
#define BM    64
#define BK    64
#define NSTEP (KLEN / BK)  // 8

typedef short bf16x8 __attribute__((ext_vector_type(8)));
typedef float f32x4  __attribute__((ext_vector_type(4)));

static __device__ __forceinline__ unsigned short f2bf(float f) {
  union { float f; unsigned u; } v; v.f = f;
  return (unsigned short)((v.u + 0x7FFFu + ((v.u >> 16) & 1u)) >> 16);  // RNE
}

// ---- prep: W1 [4096][128] f32 -> W1B fragment-packed bf16.
// W1B[((k32*8 + cf)*64 + lane)*8 + j] = bf16(W1[k32*32 + 8*(lane>>4) + j][cf*16 + (lane&15)])
// so a wave's B-fragment load for (k32, cf) is one contiguous 1KB dwordx4. ----
__global__ void prep_w1b(const float* __restrict__ W1, unsigned short* __restrict__ W1B) {
  int t = threadIdx.x;
  int gi = (blockIdx.x << 2) + (t >> 6);   // k32*8 + cf, 0..1023
  int lane = t & 63;
  int k32 = gi >> 3, cf = gi & 7;
  int kb = (k32 << 5) + ((lane >> 4) << 3);
  int c = (cf << 4) + (lane & 15);
  union { bf16x8 v; unsigned short u[8]; } o;
#pragma unroll
  for (int j = 0; j < 8; j++)
    o.u[j] = f2bf(W1[(size_t)(kb + j) * H1 + c]);
  *(bf16x8*)(W1B + (((size_t)gi << 6) + lane) * 8) = o.v;
}

// ---- prep: decoders flat [4096][32] f32 -> decT [32][4096] f32 ----
__global__ void prep_dect(const float* __restrict__ dec, float* __restrict__ decT) {
  __shared__ float tbuf[32][33];
  int d0 = blockIdx.x * 32;
  int tx = threadIdx.x & 31, ty = threadIdx.x >> 5;
#pragma unroll
  for (int i = 0; i < 32; i += 8)
    tbuf[ty + i][tx] = dec[(size_t)(d0 + ty + i) * LAT + tx];
  __syncthreads();
#pragma unroll
  for (int i = 0; i < 32; i += 8)
    decT[(size_t)(ty + i) * DIN + (d0 + tx)] = tbuf[tx][ty + i];
}

// ---- gemm1: partial[si][8192][128] = x[:, slice si] @ W1[slice si, :].
// Block: 64 rows x 128 cols x KLEN. A: reg-staged coalesced f32 -> bf16 ->
// XOR-swizzled LDS (dbuf). B: coalesced fragment loads from packed W1B (L2).
// Waves 2x2: wave (wm,wn) owns rows wm*32..+32, cols wn*64..+64. ----
__global__ __launch_bounds__(256, 4) void gemm1_kernel(
    const float* __restrict__ x, const unsigned short* __restrict__ W1B,
    float* __restrict__ partial) {
  __shared__ unsigned short As[2][BM * BK];
  const int t = threadIdx.x;
  const int mt = blockIdx.x >> 3;
  const int si = blockIdx.x & 7;
  const int rbase = mt << 6;
  const int k0 = si * KLEN;

  const int wid = t >> 6, lane = t & 63;
  const int wm = wid >> 1, wn = wid & 1;
  const int fr = lane & 15, g = lane >> 4;

  // staging: thread t -> row t>>2, 64B chunk t&3 (16 f32); writes 2 swizzled
  // 16B slots. logical slot s (8 bf16) at byte row*128 + (s^(row&7))*16.
  const int srow = t >> 2, sq = t & 3;
  const float* xp = x + (size_t)(rbase + srow) * DIN + k0 + (sq << 4);
  const int ws0 = (((sq << 1) ^ (srow & 7)) << 3);
  const int ws1 = ((((sq << 1) | 1) ^ (srow & 7)) << 3);
  unsigned short* wrow = &As[0][0] + srow * BK;

  // compute read bases: A row = wm*32 + rg*16 + fr (swizzle key fr&7 for both rg)
  const int sw = fr & 7;
  const int aoff0 = (((wm << 5) + fr) * BK);
  const int aoff1 = aoff0 + (BK << 4);
  const unsigned short* bbase =
      W1B + ((((size_t)(k0 >> 5) << 3) + (wn << 2)) << 9) + ((size_t)lane << 3);

  f32x4 acc[2][4];
#pragma unroll
  for (int i = 0; i < 2; i++)
#pragma unroll
    for (int j = 0; j < 4; j++) acc[i][j] = (f32x4){0.f, 0.f, 0.f, 0.f};

  // prologue: stage step 0
  {
    f32x4 s0 = *(const f32x4*)(xp);
    f32x4 s1 = *(const f32x4*)(xp + 4);
    f32x4 s2 = *(const f32x4*)(xp + 8);
    f32x4 s3 = *(const f32x4*)(xp + 12);
    union { bf16x8 v; unsigned short u[8]; } o0, o1;
#pragma unroll
    for (int j = 0; j < 4; j++) {
      o0.u[j] = f2bf(s0[j]); o0.u[4 + j] = f2bf(s1[j]);
      o1.u[j] = f2bf(s2[j]); o1.u[4 + j] = f2bf(s3[j]);
    }
    *(bf16x8*)(wrow + ws0) = o0.v;
    *(bf16x8*)(wrow + ws1) = o1.v;
  }
  __syncthreads();

  for (int step = 0; step < NSTEP; ++step) {
    const int cur = step & 1;
    f32x4 s0, s1, s2, s3;
    const bool more = (step + 1) < NSTEP;
    if (more) {  // issue next-tile A loads early; ds_write after compute (T14)
      const float* np = xp + (step + 1) * BK;
      s0 = *(const f32x4*)(np);
      s1 = *(const f32x4*)(np + 4);
      s2 = *(const f32x4*)(np + 8);
      s3 = *(const f32x4*)(np + 12);
    }
    const unsigned short* ab = &As[cur][0];
#pragma unroll
    for (int ss = 0; ss < 2; ss++) {
      bf16x8 bv[4];
#pragma unroll
      for (int cg = 0; cg < 4; cg++)
        bv[cg] = *(const bf16x8*)(bbase + ((size_t)((((step << 1) + ss) << 3) + cg) << 9));
      const int so = ((((ss << 2) + g) ^ sw) << 3);
      bf16x8 a0 = *(const bf16x8*)(ab + aoff0 + so);
      bf16x8 a1 = *(const bf16x8*)(ab + aoff1 + so);
#pragma unroll
      for (int cg = 0; cg < 4; cg++) {
        acc[0][cg] = __builtin_amdgcn_mfma_f32_16x16x32_bf16(a0, bv[cg], acc[0][cg], 0, 0, 0);
        acc[1][cg] = __builtin_amdgcn_mfma_f32_16x16x32_bf16(a1, bv[cg], acc[1][cg], 0, 0, 0);
      }
    }
    if (more) {
      unsigned short* w = wrow + (cur ^ 1) * (BM * BK);
      union { bf16x8 v; unsigned short u[8]; } o0, o1;
#pragma unroll
      for (int j = 0; j < 4; j++) {
        o0.u[j] = f2bf(s0[j]); o0.u[4 + j] = f2bf(s1[j]);
        o1.u[j] = f2bf(s2[j]); o1.u[4 + j] = f2bf(s3[j]);
      }
      *(bf16x8*)(w + ws0) = o0.v;
      *(bf16x8*)(w + ws1) = o1.v;
    }
    __syncthreads();
  }

  // C/D layout (HW-verified): col = lane&15, row = (lane>>4)*4 + j
  float* pb = partial + ((size_t)si * BATCH + rbase + (wm << 5)) * H1 + (wn << 6);
#pragma unroll
  for (int rg = 0; rg < 2; rg++)
#pragma unroll
    for (int cg = 0; cg < 4; cg++)
#pragma unroll
      for (int j = 0; j < 4; j++)
        pb[(size_t)((rg << 4) + (g << 2) + j) * H1 + (cg << 4) + fr] = acc[rg][cg][j];
}

// ---- z_kernel: h = relu(sum partials + b1); z = h@W2+b2 -> zout;
//      zsum fold -> zsumg [BATCH][32]. 16 rows / block. ----
__global__ __launch_bounds__(256) void z_kernel(
    const float* __restrict__ partial,
    const float* __restrict__ b1, const float* __restrict__ W2,
    const float* __restrict__ b2,
    float* __restrict__ zout, float* __restrict__ zsumg) {
  __shared__ float hs[16][128];
  __shared__ float zsp[16][32][4];
  int t = threadIdx.x;
  int rbase = blockIdx.x << 4;

#pragma unroll
  for (int i = 0; i < 8; i++) {
    int idx = t + (i << 8);
    int r = idx >> 7, c = idx & 127;
    float s = b1[c];
#pragma unroll
    for (int si = 0; si < KS; si++)
      s += partial[((size_t)si * BATCH + rbase + r) * H1 + c];
    hs[r][c] = fmaxf(s, 0.f);
  }
  __syncthreads();

  int wq = t >> 6, lane = t & 63;
  int c0 = (wq << 7) + lane;
  float acc0[16], acc1[16];
#pragma unroll
  for (int r = 0; r < 16; r++) { acc0[r] = 0.f; acc1[r] = 0.f; }
  for (int k4 = 0; k4 < 32; k4++) {
    float w2a[4], w2b[4];
#pragma unroll
    for (int j = 0; j < 4; j++) {
      w2a[j] = W2[(size_t)(k4 * 4 + j) * NLAT + c0];
      w2b[j] = W2[(size_t)(k4 * 4 + j) * NLAT + c0 + 64];
    }
#pragma unroll
    for (int rg = 0; rg < 4; rg++) {
      f32x4 hv[4];
#pragma unroll
      for (int rr = 0; rr < 4; rr++)
        hv[rr] = *(const f32x4*)&hs[rg * 4 + rr][k4 * 4];
#pragma unroll
      for (int rr = 0; rr < 4; rr++)
#pragma unroll
        for (int j = 0; j < 4; j++) {
          acc0[rg * 4 + rr] += hv[rr][j] * w2a[j];
          acc1[rg * 4 + rr] += hv[rr][j] * w2b[j];
        }
    }
  }
  float bb0 = b2[c0], bb1 = b2[c0 + 64];
#pragma unroll
  for (int r = 0; r < 16; r++) {
    float v0 = acc0[r] + bb0, v1 = acc1[r] + bb1;
    zout[(size_t)(rbase + r) * NLAT + c0] = v0;
    zout[(size_t)(rbase + r) * NLAT + c0 + 64] = v1;
    float ps = v0 + v1;
    ps += __shfl_xor(ps, 32);
    if (lane < 32) zsp[r][lane][wq] = ps;
  }
  __syncthreads();
#pragma unroll
  for (int i = 0; i < 2; i++) {
    int idx = t + (i << 8);
    int r = idx >> 5, l = idx & 31;
    f32x4 p4 = *(const f32x4*)&zsp[r][l][0];
    zsumg[(size_t)(rbase + r) * LAT + l] = p4[0] + p4[1] + p4[2] + p4[3];
  }
}

// ---- recon_kernel: rout[b][d] = sum_l zsum[b][l] * decT[l][d]. ----
__global__ __launch_bounds__(256) void recon_kernel(
    const float* __restrict__ zsumg, const float* __restrict__ decT,
    float* __restrict__ rout) {
  __shared__ float zs[32][32];
  int t = threadIdx.x;
  int rbase = (blockIdx.x >> 4) << 5;
  int dcol0 = (blockIdx.x & 15) << 8;
  {
    int r = t >> 3, c4 = (t & 7) << 2;
    *(f32x4*)&zs[r][c4] = *(const f32x4*)(zsumg + (size_t)(rbase + r) * LAT + c4);
  }
  __syncthreads();
  int wq = t >> 6, lane = t & 63;
  int r0 = wq << 3;
  int dcol = dcol0 + (lane << 2);
  f32x4 acc[8];
#pragma unroll
  for (int r = 0; r < 8; r++) acc[r] = (f32x4){0.f, 0.f, 0.f, 0.f};
#pragma unroll 8
  for (int l = 0; l < 32; l++) {
    f32x4 dv = *(const f32x4*)(decT + (size_t)l * DIN + dcol);
#pragma unroll
    for (int r = 0; r < 8; r++) {
      float zv = zs[r0 + r][l];
#pragma unroll
      for (int j = 0; j < 4; j++) acc[r][j] += zv * dv[j];
    }
  }
#pragma unroll
  for (int r = 0; r < 8; r++)
    *(f32x4*)(rout + (size_t)(rbase + r0 + r) * DIN + dcol) = acc[r];
}

extern "C" void kernel_launch(void* const* d_in, const int* in_sizes, int n_in,
                              void* d_out, int out_size, void* d_ws, size_t ws_size,
                              hipStream_t stream) {
  const float* x   = (const float*)d_in[0];
  const float* W1  = (const float*)d_in[1];
  const float* b1  = (const float*)d_in[2];
  const float* W2  = (const float*)d_in[3];
  const float* b2  = (const float*)d_in[4];
  const float* dec = (const float*)d_in[5];
  float* zout = (float*)d_out;
  float* rout = zout + (size_t)BATCH * NLAT;

  char* ws = (char*)d_ws;
  unsigned short* W1B = (unsigned short*)ws;                 // 1 MB
  float* decT  = (float*)(ws + (1u << 20));                  // 512 KB
  float* zsumg = (float*)(ws + (1u << 20) + (512u << 10));   // 1 MB
  // partial [KS][BATCH][H1] f32 = 32 MB lives in the recon output region
  // (134 MB); z_kernel consumes it before recon_kernel overwrites it.
  float* partial = rout;

  prep_w1b<<<dim3(256), 256, 0, stream>>>(W1, W1B);
  prep_dect<<<dim3(128), 256, 0, stream>>>(dec, decT);
  gemm1_kernel<<<dim3((BATCH / BM) * KS), 256, 0, stream>>>(x, W1B, partial);
  z_kernel<<<dim3(512), 256, 0, stream>>>(partial, b1, W2, b2, zout, zsumg);
  recon_kernel<<<dim3(4096), 256, 0, stream>>>(zsumg, decT, rout);
}

// Round 5
// 91.059 us; speedup vs baseline: 1.8803x; 1.2874x over previous
//
#include <hip/hip_runtime.h>
#include <hip/hip_bf16.h>

#define BATCH 8192
#define DIN   4096
#define H1    128
#define NLAT  512
#define LAT   32
#define BM    32
#define BK    128
#define NSTEP (DIN / BK)   // 32
#define APITCH 136         // ushorts per LDS row (128 + 8 pad -> bank spread)

typedef short bf16x8 __attribute__((ext_vector_type(8)));
typedef float f32x4  __attribute__((ext_vector_type(4)));

static __device__ __forceinline__ unsigned short f2bf(float f) {
  union { float f; unsigned u; } v; v.f = f;
  return (unsigned short)((v.u + 0x7FFFu + ((v.u >> 16) & 1u)) >> 16);  // RNE
}

// ---- prep_all: three independent repacks, branched on blockIdx.
// b in [0,256):   W1 [4096][128] -> W1B fragment-packed bf16 (1 MB)
// b in [256,288): W2 [128][512]  -> W2B fragment-packed bf16 (128 KB)
// b in [288,416): decoders [G,K,L] flat [4096][32] -> decT [32][4096] f32
// Fragment packing: group gi=(k32, cf): lane(g=lane>>4, fr=lane&15), elem j
//   holds W[k32*32 + g*8 + j][cf*16 + fr] -> wave load = contiguous 1KB. ----
__global__ void prep_all(const float* __restrict__ W1, const float* __restrict__ W2,
                         const float* __restrict__ dec,
                         unsigned short* __restrict__ W1B,
                         unsigned short* __restrict__ W2B,
                         float* __restrict__ decT) {
  int b = blockIdx.x;
  int t = threadIdx.x;
  if (b < 256) {
    int gi = (b << 2) + (t >> 6);         // k32*8 + cf, 0..1023
    int lane = t & 63;
    int kb = ((gi >> 3) << 5) + ((lane >> 4) << 3);
    int c = ((gi & 7) << 4) + (lane & 15);
    union { bf16x8 v; unsigned short u[8]; } o;
#pragma unroll
    for (int j = 0; j < 8; j++) o.u[j] = f2bf(W1[(size_t)(kb + j) * H1 + c]);
    *(bf16x8*)(W1B + (((size_t)gi << 6) + lane) * 8) = o.v;
  } else if (b < 288) {
    int gi = ((b - 256) << 2) + (t >> 6); // k32*32 + cf, 0..127
    int lane = t & 63;
    int kb = ((gi >> 5) << 5) + ((lane >> 4) << 3);
    int c = ((gi & 31) << 4) + (lane & 15);
    union { bf16x8 v; unsigned short u[8]; } o;
#pragma unroll
    for (int j = 0; j < 8; j++) o.u[j] = f2bf(W2[(size_t)(kb + j) * NLAT + c]);
    *(bf16x8*)(W2B + (((size_t)gi << 6) + lane) * 8) = o.v;
  } else {
    __shared__ float tbuf[32][33];
    int d0 = (b - 288) * 32;
    int tx = t & 31, ty = t >> 5;
#pragma unroll
    for (int i = 0; i < 32; i += 8)
      tbuf[ty + i][tx] = dec[(size_t)(d0 + ty + i) * LAT + tx];
    __syncthreads();
#pragma unroll
    for (int i = 0; i < 32; i += 8)
      decT[(size_t)(ty + i) * DIN + (d0 + tx)] = tbuf[tx][ty + i];
  }
}

// ---- enc_kernel: fused  h = relu(x@W1+b1);  z = h@W2+b2 -> zout;
//      zsum (fold over 16 factors) -> zsumg [BATCH][32].
// Grid: 256 blocks (1/CU) x 512 thr (8 waves). Block: 32 rows, full K=4096.
// Phase A: x LDS-staged (1-barrier dbuf, loads issued early), W1B frags from
// L2. Wave w: 32 rows x cols w*16..+16 (acc[2] f32x4). Phase B: h (bf16, LDS)
// @ W2B: wave w: 32 rows x cols w*64..+64 (acc2[2][4]). ----
__global__ __launch_bounds__(512, 2) void enc_kernel(
    const float* __restrict__ x, const unsigned short* __restrict__ W1B,
    const unsigned short* __restrict__ W2B,
    const float* __restrict__ b1, const float* __restrict__ b2,
    float* __restrict__ zout, float* __restrict__ zsumg) {
  __shared__ unsigned short As[2][BM * APITCH];
  __shared__ unsigned short hs[BM * APITCH];
  __shared__ float zsp[8][32][32];

  const int t = threadIdx.x;
  const int rbase = blockIdx.x << 5;
  const int w = t >> 6, lane = t & 63;
  const int g = lane >> 4, fr = lane & 15;

  // staging: thread -> row t>>4, 8 f32 at k-offset (t&15)*8 (32B coalesced)
  const int srow = t >> 4, skq = (t & 15) << 3;
  const float* xp = x + (size_t)(rbase + srow) * DIN + skq;
  const int wofs = srow * APITCH + skq;

  f32x4 acc[2];
  acc[0] = (f32x4){0.f, 0.f, 0.f, 0.f};
  acc[1] = (f32x4){0.f, 0.f, 0.f, 0.f};

  // prologue: stage step 0
  {
    f32x4 ra0 = *(const f32x4*)xp;
    f32x4 ra1 = *(const f32x4*)(xp + 4);
    union { bf16x8 v; unsigned short u[8]; } o;
#pragma unroll
    for (int j = 0; j < 4; j++) { o.u[j] = f2bf(ra0[j]); o.u[4 + j] = f2bf(ra1[j]); }
    *(bf16x8*)(&As[0][wofs]) = o.v;
  }
  __syncthreads();

  for (int s = 0; s < NSTEP; ++s) {
    f32x4 ra0, ra1;
    const bool more = (s + 1) < NSTEP;
    if (more) {  // issue next-step loads before compute (hide HBM latency)
      ra0 = *(const f32x4*)(xp + (s + 1) * BK);
      ra1 = *(const f32x4*)(xp + (s + 1) * BK + 4);
    }
    const unsigned short* ab = &As[s & 1][0];
#pragma unroll
    for (int k32 = 0; k32 < 4; ++k32) {
      bf16x8 bv = *(const bf16x8*)(W1B + (((size_t)(((s << 2) + k32) << 3) + w) << 9) + (lane << 3));
      bf16x8 a0 = *(const bf16x8*)(ab + fr * APITCH + (((k32 << 2) + g) << 3));
      bf16x8 a1 = *(const bf16x8*)(ab + (16 + fr) * APITCH + (((k32 << 2) + g) << 3));
      acc[0] = __builtin_amdgcn_mfma_f32_16x16x32_bf16(a0, bv, acc[0], 0, 0, 0);
      acc[1] = __builtin_amdgcn_mfma_f32_16x16x32_bf16(a1, bv, acc[1], 0, 0, 0);
    }
    // single barrier per step: write target != read target; prior step's
    // barrier already separates us from the last readers of As[(s+1)&1].
    if (more) {
      union { bf16x8 v; unsigned short u[8]; } o;
#pragma unroll
      for (int j = 0; j < 4; j++) { o.u[j] = f2bf(ra0[j]); o.u[4 + j] = f2bf(ra1[j]); }
      *(bf16x8*)(&As[(s + 1) & 1][wofs]) = o.v;
    }
    __syncthreads();
  }

  // phase A epilogue: +b1, relu, -> hs (bf16). C/D: col=fr, row=g*4+j.
  {
    const int col = (w << 4) + fr;
    const float b1v = b1[col];
#pragma unroll
    for (int rg = 0; rg < 2; rg++)
#pragma unroll
      for (int j = 0; j < 4; j++) {
        float h = fmaxf(acc[rg][j] + b1v, 0.f);
        hs[((rg << 4) + (g << 2) + j) * APITCH + col] = f2bf(h);
      }
  }
  __syncthreads();

  // phase B: z = h @ W2 + b2. Wave w: cols w*64..+64 (cf = w*4+cfl), K=128.
  f32x4 acc2[2][4];
#pragma unroll
  for (int i = 0; i < 2; i++)
#pragma unroll
    for (int j = 0; j < 4; j++) acc2[i][j] = (f32x4){0.f, 0.f, 0.f, 0.f};
#pragma unroll
  for (int k32 = 0; k32 < 4; ++k32) {
    bf16x8 a0 = *(const bf16x8*)(hs + fr * APITCH + (((k32 << 2) + g) << 3));
    bf16x8 a1 = *(const bf16x8*)(hs + (16 + fr) * APITCH + (((k32 << 2) + g) << 3));
#pragma unroll
    for (int cfl = 0; cfl < 4; ++cfl) {
      bf16x8 bv = *(const bf16x8*)(W2B + (((size_t)((k32 << 5) + (w << 2) + cfl)) << 9) + (lane << 3));
      acc2[0][cfl] = __builtin_amdgcn_mfma_f32_16x16x32_bf16(a0, bv, acc2[0][cfl], 0, 0, 0);
      acc2[1][cfl] = __builtin_amdgcn_mfma_f32_16x16x32_bf16(a1, bv, acc2[1][cfl], 0, 0, 0);
    }
  }

  // epilogue: z write + zsum fold.
  // col = w*64 + cfl*16 + fr; latent = (cfl&1)*16 + fr; factor = w*2 + cfl/2.
  {
    float b2v[4];
#pragma unroll
    for (int cfl = 0; cfl < 4; ++cfl) b2v[cfl] = b2[(w << 6) + (cfl << 4) + fr];
#pragma unroll
    for (int rg = 0; rg < 2; rg++) {
      f32x4 zv[4];
#pragma unroll
      for (int cfl = 0; cfl < 4; ++cfl) {
#pragma unroll
        for (int j = 0; j < 4; j++) zv[cfl][j] = acc2[rg][cfl][j] + b2v[cfl];
        const int row = rbase + (rg << 4) + (g << 2);
        const int col = (w << 6) + (cfl << 4) + fr;
#pragma unroll
        for (int j = 0; j < 4; j++)
          zout[(size_t)(row + j) * NLAT + col] = zv[cfl][j];
      }
      // zsum partials for this wave's 2 factors
#pragma unroll
      for (int j = 0; j < 4; j++) {
        const int row = (rg << 4) + (g << 2) + j;
        zsp[w][row][fr]      = zv[0][j] + zv[2][j];
        zsp[w][row][16 + fr] = zv[1][j] + zv[3][j];
      }
    }
  }
  __syncthreads();
  // reduce 8 wave-partials -> zsumg (deterministic)
#pragma unroll
  for (int i = 0; i < 2; i++) {
    int idx = t + (i << 9);
    int r = idx >> 5, l = idx & 31;
    float s = 0.f;
#pragma unroll
    for (int w8 = 0; w8 < 8; w8++) s += zsp[w8][r][l];
    zsumg[(size_t)(rbase + r) * LAT + l] = s;
  }
}

// ---- recon_kernel: rout[b][d] = sum_l zsum[b][l] * decT[l][d]. ----
__global__ __launch_bounds__(256) void recon_kernel(
    const float* __restrict__ zsumg, const float* __restrict__ decT,
    float* __restrict__ rout) {
  __shared__ float zs[32][32];
  int t = threadIdx.x;
  int rbase = (blockIdx.x >> 4) << 5;
  int dcol0 = (blockIdx.x & 15) << 8;
  {
    int r = t >> 3, c4 = (t & 7) << 2;
    *(f32x4*)&zs[r][c4] = *(const f32x4*)(zsumg + (size_t)(rbase + r) * LAT + c4);
  }
  __syncthreads();
  int wq = t >> 6, lane = t & 63;
  int r0 = wq << 3;
  int dcol = dcol0 + (lane << 2);
  f32x4 acc[8];
#pragma unroll
  for (int r = 0; r < 8; r++) acc[r] = (f32x4){0.f, 0.f, 0.f, 0.f};
#pragma unroll 8
  for (int l = 0; l < 32; l++) {
    f32x4 dv = *(const f32x4*)(decT + (size_t)l * DIN + dcol);
#pragma unroll
    for (int r = 0; r < 8; r++) {
      float zv = zs[r0 + r][l];
#pragma unroll
      for (int j = 0; j < 4; j++) acc[r][j] += zv * dv[j];
    }
  }
#pragma unroll
  for (int r = 0; r < 8; r++)
    *(f32x4*)(rout + (size_t)(rbase + r0 + r) * DIN + dcol) = acc[r];
}

extern "C" void kernel_launch(void* const* d_in, const int* in_sizes, int n_in,
                              void* d_out, int out_size, void* d_ws, size_t ws_size,
                              hipStream_t stream) {
  const float* x   = (const float*)d_in[0];
  const float* W1  = (const float*)d_in[1];
  const float* b1  = (const float*)d_in[2];
  const float* W2  = (const float*)d_in[3];
  const float* b2  = (const float*)d_in[4];
  const float* dec = (const float*)d_in[5];
  float* zout = (float*)d_out;
  float* rout = zout + (size_t)BATCH * NLAT;

  char* ws = (char*)d_ws;
  unsigned short* W1B = (unsigned short*)ws;                          // 1 MB
  unsigned short* W2B = (unsigned short*)(ws + (1u << 20));           // 128 KB
  float* decT  = (float*)(ws + (1u << 20) + (1u << 17));              // 512 KB
  float* zsumg = (float*)(ws + (1u << 20) + (1u << 17) + (1u << 19)); // 1 MB

  prep_all<<<dim3(416), 256, 0, stream>>>(W1, W2, dec, W1B, W2B, decT);
  enc_kernel<<<dim3(BATCH / BM), 512, 0, stream>>>(x, W1B, W2B, b1, b2, zout, zsumg);
  recon_kernel<<<dim3(4096), 256, 0, stream>>>(zsumg, decT, rout);
}